// Round 5
// baseline (210.850 us; speedup 1.0000x reference)
//
#include <hip/hip_runtime.h>
#include <stdint.h>

// ---------------------------------------------------------------------------
// MultiheadMaskedAttention (B=2, S=2048, H=1024, 16 heads x d=64)
// R5: attn rescheduled — 2048 fine-grained blocks (head x 32-row q-tile),
// 4-way strided KV split per block (balanced), big-tiles-first dispatch,
// launch_bounds(256,3) (no forced spills), V loads at iter top + in-place
// next-K prefetch after last use. GEMMs/prep unchanged.
// ---------------------------------------------------------------------------

typedef __bf16 bf16;
typedef __attribute__((ext_vector_type(8))) __bf16 bf16x8;
typedef __attribute__((ext_vector_type(4))) __bf16 bf16x4;
typedef __attribute__((ext_vector_type(4))) float floatx4;

#define SCL 0.18033688011112042f  // (1/sqrt(64)) * log2(e)

__device__ __forceinline__ floatx4 mfma_bf16(bf16x8 a, bf16x8 b, floatx4 c) {
  // A frag: m=lane&15, k=quad*8+j ; B frag: n=lane&15, k=quad*8+j
  // D frag: n=lane&15, m=quad*4+reg   [verified m89/m91]
  return __builtin_amdgcn_mfma_f32_16x16x32_bf16(a, b, c, 0, 0, 0);
}

__device__ __forceinline__ void cp_g2l_16(const bf16* g, bf16* l) {
  __builtin_amdgcn_global_load_lds(
      (const __attribute__((address_space(1))) void*)g,
      (__attribute__((address_space(3))) void*)l, 16, 0, 0);
}

// ---- merged prep: cast x -> bf16 ; cast+transpose w_qkv, w_o ----
__global__ __launch_bounds__(256) void prep_kernel(
    const float* __restrict__ x, bf16* __restrict__ xb,
    const float* __restrict__ w_qkv, bf16* __restrict__ wqkvt,
    const float* __restrict__ w_o, bf16* __restrict__ wot) {
  const int b = blockIdx.x;
  const int tid = threadIdx.x;
  if (b < 4096) {
    const int i = (b * 256 + tid) * 4;
    floatx4 v = *(const floatx4*)(x + i);
    bf16x4 o;
    o[0] = (bf16)v[0]; o[1] = (bf16)v[1]; o[2] = (bf16)v[2]; o[3] = (bf16)v[3];
    *(bf16x4*)(xb + i) = o;
    return;
  }
  __shared__ float tile[32][33];
  const float* W; bf16* Wt; int K, N, n0, k0;
  if (b < 7168) {
    const int bb = b - 4096;
    W = w_qkv; Wt = wqkvt; K = 1024; N = 3072;
    n0 = (bb % 96) * 32; k0 = (bb / 96) * 32;
  } else {
    const int bb = b - 7168;
    W = w_o; Wt = wot; K = 1024; N = 1024;
    n0 = (bb & 31) * 32; k0 = (bb >> 5) * 32;
  }
  const int tx = tid & 31, ty = tid >> 5;
  for (int i = 0; i < 4; ++i)
    tile[ty + 8 * i][tx] = W[(size_t)(k0 + ty + 8 * i) * N + n0 + tx];
  __syncthreads();
  for (int i = 0; i < 4; ++i)
    Wt[(size_t)(n0 + ty + 8 * i) * K + k0 + tx] = (bf16)tile[tx][ty + 8 * i];
}

// ---- GEMM: C = A(M x K bf16 rm) * Bt(N x K bf16 rm)^T + bias ----
template <int MODE, int MI>
__global__ __launch_bounds__(256, 3) void gemm_bt_kernel(
    const bf16* __restrict__ A, const bf16* __restrict__ Bt,
    const float* __restrict__ bias, float* __restrict__ outF,
    bf16* __restrict__ qb, bf16* __restrict__ kb, bf16* __restrict__ vtb,
    int N, int K) {
  constexpr int BM = MI * 32;
  __shared__ bf16 As[BM * 32];
  __shared__ bf16 Bs[128 * 32];
  const int tid = threadIdx.x;
  const int w = tid >> 6, lane = tid & 63;
  const int l16 = lane & 15, quad = lane >> 4;
  const int m0 = blockIdx.y * BM, n0 = blockIdx.x * 128;
  const int wm = (w & 1) * (BM / 2), wn = (w >> 1) * 64;

  const int arow = w * (BM / 4) + (lane >> 2);
  const int acol = (lane & 3) * 8;
  const bf16* Ag = A + (size_t)(m0 + arow) * K + acol;
  bf16* Al = As + arow * 32 + acol;
  const int brow = w * 32 + (lane >> 2);
  const bf16* Bg = Bt + (size_t)(n0 + brow) * K + acol;
  bf16* Bl = Bs + brow * 32 + acol;

  floatx4 acc[MI][4];
#pragma unroll
  for (int i = 0; i < MI; ++i)
#pragma unroll
    for (int j = 0; j < 4; ++j) acc[i][j] = (floatx4){0.f, 0.f, 0.f, 0.f};

  for (int k0 = 0; k0 < K; k0 += 32) {
    __syncthreads();
    cp_g2l_16(Ag + k0, Al);
    if (MI == 4) cp_g2l_16(Ag + (size_t)16 * K + k0, Al + 16 * 32);
    cp_g2l_16(Bg + k0, Bl);
    cp_g2l_16(Bg + (size_t)16 * K + k0, Bl + 16 * 32);
    __syncthreads();
    bf16x8 af[MI], bfr[4];
#pragma unroll
    for (int i = 0; i < MI; ++i)
      af[i] = *(const bf16x8*)(&As[(wm + i * 16 + l16) * 32 + quad * 8]);
#pragma unroll
    for (int j = 0; j < 4; ++j)
      bfr[j] = *(const bf16x8*)(&Bs[(wn + j * 16 + l16) * 32 + quad * 8]);
#pragma unroll
    for (int i = 0; i < MI; ++i)
#pragma unroll
      for (int j = 0; j < 4; ++j)
        acc[i][j] = mfma_bf16(af[i], bfr[j], acc[i][j]);
  }

#pragma unroll
  for (int i = 0; i < MI; ++i)
#pragma unroll
    for (int j = 0; j < 4; ++j) {
      const int nn = n0 + wn + j * 16 + l16;
      const float bv = bias[nn];
      const int mbase = m0 + wm + i * 16 + quad * 4;
      if (MODE == 1) {
#pragma unroll
        for (int r = 0; r < 4; ++r)
          outF[(size_t)(mbase + r) * N + nn] = acc[i][j][r] + bv;
      } else {
        const int which = nn >> 10;  // uniform per block
        const int rem = nn & 1023;
        const int h = rem >> 6, d = rem & 63;
        const int b = mbase >> 11, s = mbase & 2047;
        const size_t bh = (size_t)(b * 16 + h);
        if (which == 2) {
          bf16x4 pk;
#pragma unroll
          for (int r = 0; r < 4; ++r) pk[r] = (bf16)(acc[i][j][r] + bv);
          *(bf16x4*)(vtb + (bh * 64 + d) * 2048 + s) = pk;
        } else if (which == 0) {
#pragma unroll
          for (int r = 0; r < 4; ++r)
            qb[(bh * 2048 + s + r) * 64 + d] = (bf16)((acc[i][j][r] + bv) * SCL);
        } else {
#pragma unroll
          for (int r = 0; r < 4; ++r)
            kb[(bh * 2048 + s + r) * 64 + d] = (bf16)(acc[i][j][r] + bv);
        }
      }
    }
}

// ---- Flash attention, causal, max-free softmax. ----
// 2048 blocks: block = (head, 32-row q-tile), big tiles dispatched first.
// 4 waves split the tile's KV range strided (t = w, w+4, ...): balanced to
// +-1 iter. Partials (linear: O, l) combined via LDS tree. Q pre-scaled by
// log2e/8; l via all-ones-B MFMA; raw v_exp_f32.
__global__ __launch_bounds__(256, 3) void attn_kernel(
    const bf16* __restrict__ Qb, const bf16* __restrict__ Kb,
    const bf16* __restrict__ Vtb, bf16* __restrict__ attnb) {
  __shared__ __align__(16) char smem[20480];  // P (4x4736B) U 2 combine slots
  const int bid = blockIdx.x;
  const int bh = (bid & 7) * 4 + ((bid >> 3) & 3);  // 4 heads per XCD
  const int qt = 63 - (bid >> 5);                   // big q-tiles first
  const int tid = threadIdx.x;
  const int w = tid >> 6, lane = tid & 63;
  const int l16 = lane & 15, quad = lane >> 4;
  const int q0 = qt * 32;
  const int b = bh >> 4, h = bh & 15;
  const bf16* Qh = Qb + (size_t)bh * 2048 * 64;
  const bf16* Kh = Kb + (size_t)bh * 2048 * 64;
  const bf16* Vh = Vtb + (size_t)bh * 64 * 2048;
  bf16* Pw = (bf16*)smem + w * 2368;
  const int pw_wr = quad * 288 + (quad >> 1) * 16 + l16;    // row=quad*4+r
  const int pw_rd = l16 * 72 + (l16 >> 3) * 16 + quad * 8;  // row=l16

  const int nt = (qt >> 1) + 1;  // KV tiles for this q-tile
  const int tdiag = nt - 1;

  bf16x8 qf[2][2];
#pragma unroll
  for (int mb = 0; mb < 2; ++mb)
#pragma unroll
    for (int kq = 0; kq < 2; ++kq)
      qf[mb][kq] = *(const bf16x8*)(Qh + (size_t)(q0 + mb * 16 + l16) * 64 +
                                    kq * 32 + quad * 8);
  bf16x8 ones;
#pragma unroll
  for (int j = 0; j < 8; ++j) ones[j] = (bf16)1.0f;

  floatx4 O[2][4], Ol[2];
#pragma unroll
  for (int mb = 0; mb < 2; ++mb) {
#pragma unroll
    for (int nd = 0; nd < 4; ++nd) O[mb][nd] = (floatx4){0.f, 0.f, 0.f, 0.f};
    Ol[mb] = (floatx4){0.f, 0.f, 0.f, 0.f};
  }

  // prologue K frags for t = w (clamped addr; unused if w >= nt)
  bf16x8 kf[4][2];
  {
    const bf16* Kt = Kh + (size_t)(w < nt ? w : 0) * 64 * 64;
#pragma unroll
    for (int nk = 0; nk < 4; ++nk)
#pragma unroll
      for (int kq = 0; kq < 2; ++kq)
        kf[nk][kq] =
            *(const bf16x8*)(Kt + (nk * 16 + l16) * 64 + kq * 32 + quad * 8);
  }

  for (int t = w; t < nt; t += 4) {
    const bool diag = (t == tdiag);
    const bf16* Vt = Vh + (size_t)t * 64;

    // V frags first (latency hidden under QK + exp)
    bf16x8 vf[4][2];
#pragma unroll
    for (int nd = 0; nd < 4; ++nd)
#pragma unroll
      for (int kq = 0; kq < 2; ++kq)
        vf[nd][kq] =
            *(const bf16x8*)(Vt + (nd * 16 + l16) * 2048 + kq * 32 + quad * 8);

    // ---- mb0: QK -> exp -> P write ----
    {
      floatx4 sf[4];
#pragma unroll
      for (int nk = 0; nk < 4; ++nk) {
        floatx4 a = (floatx4){0.f, 0.f, 0.f, 0.f};
        a = mfma_bf16(qf[0][0], kf[nk][0], a);
        a = mfma_bf16(qf[0][1], kf[nk][1], a);
        sf[nk] = a;
      }
#pragma unroll
      for (int nk = 0; nk < 4; ++nk)
#pragma unroll
        for (int r = 0; r < 4; ++r) {
          float s = sf[nk][r];
          if (diag) {
            const int kc = t * 64 + nk * 16 + l16;
            const int qrow = q0 + quad * 4 + r;
            s = (kc <= qrow) ? s : -1e30f;
          }
          Pw[pw_wr + r * 72 + nk * 16] = (bf16)__builtin_amdgcn_exp2f(s);
        }
    }
    // ---- mb1: QK (last use of kf) ----
    floatx4 sg[4];
#pragma unroll
    for (int nk = 0; nk < 4; ++nk) {
      floatx4 a = (floatx4){0.f, 0.f, 0.f, 0.f};
      a = mfma_bf16(qf[1][0], kf[nk][0], a);
      a = mfma_bf16(qf[1][1], kf[nk][1], a);
      sg[nk] = a;
    }
    // in-place prefetch of next K tile (t+4, clamped; unused on last iter)
    {
      const int tn = (t + 4 < nt) ? (t + 4) : 0;
      const bf16* Kt = Kh + (size_t)tn * 64 * 64;
#pragma unroll
      for (int nk = 0; nk < 4; ++nk)
#pragma unroll
        for (int kq = 0; kq < 2; ++kq)
          kf[nk][kq] =
              *(const bf16x8*)(Kt + (nk * 16 + l16) * 64 + kq * 32 + quad * 8);
    }
    // ---- mb1: exp -> P write ----
#pragma unroll
    for (int nk = 0; nk < 4; ++nk)
#pragma unroll
      for (int r = 0; r < 4; ++r) {
        float s = sg[nk][r];
        if (diag) {
          const int kc = t * 64 + nk * 16 + l16;
          const int qrow = q0 + 16 + quad * 4 + r;
          s = (kc <= qrow) ? s : -1e30f;
        }
        Pw[pw_wr + 1184 + r * 72 + nk * 16] = (bf16)__builtin_amdgcn_exp2f(s);
      }

    // ---- P C-layout -> A-layout via per-wave LDS; O += P V; l += P * 1 ----
#pragma unroll
    for (int mb = 0; mb < 2; ++mb) {
      bf16x8 pf[2];
      pf[0] = *(const bf16x8*)(&Pw[pw_rd + mb * 1184]);
      pf[1] = *(const bf16x8*)(&Pw[pw_rd + mb * 1184 + 32]);
#pragma unroll
      for (int nd = 0; nd < 4; ++nd) {
        floatx4 o = O[mb][nd];
        o = mfma_bf16(pf[0], vf[nd][0], o);
        o = mfma_bf16(pf[1], vf[nd][1], o);
        O[mb][nd] = o;
      }
      Ol[mb] = mfma_bf16(pf[0], ones, Ol[mb]);
      Ol[mb] = mfma_bf16(pf[1], ones, Ol[mb]);
    }
  }

  // ---- combine 4 partials (pure sums): tree through 2 LDS slots ----
  float* Cb = (float*)smem;  // slot s at s*2560 floats (10240 B each)
  __syncthreads();           // P region dead
  if (w >= 2) {
    float* S = Cb + (w - 2) * 2560;
#pragma unroll
    for (int mb = 0; mb < 2; ++mb) {
#pragma unroll
      for (int nd = 0; nd < 4; ++nd)
        *(floatx4*)(S + ((mb * 4 + nd) * 64 + lane) * 4) = O[mb][nd];
      *(floatx4*)(S + ((8 + mb) * 64 + lane) * 4) = Ol[mb];
    }
  }
  __syncthreads();
  if (w < 2) {
    const float* S = Cb + w * 2560;
#pragma unroll
    for (int mb = 0; mb < 2; ++mb) {
#pragma unroll
      for (int nd = 0; nd < 4; ++nd)
        O[mb][nd] += *(const floatx4*)(S + ((mb * 4 + nd) * 64 + lane) * 4);
      Ol[mb] += *(const floatx4*)(S + ((8 + mb) * 64 + lane) * 4);
    }
  }
  __syncthreads();
  if (w == 1) {
#pragma unroll
    for (int mb = 0; mb < 2; ++mb) {
#pragma unroll
      for (int nd = 0; nd < 4; ++nd)
        *(floatx4*)(Cb + ((mb * 4 + nd) * 64 + lane) * 4) = O[mb][nd];
      *(floatx4*)(Cb + ((8 + mb) * 64 + lane) * 4) = Ol[mb];
    }
  }
  __syncthreads();
  if (w == 0) {
#pragma unroll
    for (int mb = 0; mb < 2; ++mb) {
#pragma unroll
      for (int nd = 0; nd < 4; ++nd)
        O[mb][nd] += *(const floatx4*)(Cb + ((mb * 4 + nd) * 64 + lane) * 4);
      Ol[mb] += *(const floatx4*)(Cb + ((8 + mb) * 64 + lane) * 4);
    }
#pragma unroll
    for (int mb = 0; mb < 2; ++mb)
#pragma unroll
      for (int r = 0; r < 4; ++r) {
        const int qrow = q0 + mb * 16 + quad * 4 + r;
        const float inv = 1.f / Ol[mb][r];
#pragma unroll
        for (int nd = 0; nd < 4; ++nd)
          attnb[((size_t)(b * 2048 + qrow)) * 1024 + h * 64 + nd * 16 + l16] =
              (bf16)(O[mb][nd][r] * inv);
      }
  }
}

// ---------------------------------------------------------------------------
extern "C" void kernel_launch(void* const* d_in, const int* in_sizes, int n_in,
                              void* d_out, int out_size, void* d_ws, size_t ws_size,
                              hipStream_t stream) {
  const float* x     = (const float*)d_in[0];  // (2,2048,1024)
  const float* w_qkv = (const float*)d_in[1];  // (1024,3072)
  const float* b_qkv = (const float*)d_in[2];  // (3072)
  const float* w_o   = (const float*)d_in[3];  // (1024,1024)
  const float* b_o   = (const float*)d_in[4];  // (1024)
  float* out = (float*)d_out;                  // (2,2048,1024) fp32

  char* ws = (char*)d_ws;
  bf16* xb    = (bf16*)ws; ws += (size_t)4096 * 1024 * 2;
  bf16* wqkvt = (bf16*)ws; ws += (size_t)3072 * 1024 * 2;
  bf16* wot   = (bf16*)ws; ws += (size_t)1024 * 1024 * 2;
  bf16* qb    = (bf16*)ws; ws += (size_t)32 * 2048 * 64 * 2;
  bf16* kb    = (bf16*)ws; ws += (size_t)32 * 2048 * 64 * 2;
  bf16* vtb   = (bf16*)ws; ws += (size_t)32 * 2048 * 64 * 2;  // (bh,64,S)
  bf16* attnb = (bf16*)ws; ws += (size_t)4096 * 1024 * 2;

  prep_kernel<<<8192, 256, 0, stream>>>(x, xb, w_qkv, wqkvt, w_o, wot);
  gemm_bt_kernel<0, 4><<<dim3(24, 32), 256, 0, stream>>>(
      xb, wqkvt, b_qkv, nullptr, qb, kb, vtb, 3072, 1024);
  attn_kernel<<<2048, 256, 0, stream>>>(qb, kb, vtb, attnb);
  gemm_bt_kernel<1, 2><<<dim3(8, 64), 256, 0, stream>>>(
      attnb, wot, b_o, out, nullptr, nullptr, nullptr, 1024, 1024);
}